// Round 3
// baseline (67.027 us; speedup 1.0000x reference)
//
#include <hip/hip_runtime.h>

// Cox PH loss, N=8192 fp32.
// R3: 3-phase. prep: pack (survtime_j, exp(theta_j)) -> ws float2 (exp computed
// ONCE, not per-block). main: 1024 blocks x 256 thr, 8 i's/thread in regs,
// 2 j's per float4 load -> 48 VALU per 16B load (~90% useful-VALU).
// fin: reduce 1024 block partials. Fixed harness cost: 268MB ws re-poison
// (~40 us fillBuffer) dominates dur_us; our controllable part targets ~7 us.

#define COX_N 8192
#define TPB   256
#define IPB   8                  // i's per block (register accumulators)
#define NBLK  (COX_N / IPB)      // 1024 blocks -> 4 blocks/CU -> 16 waves/CU
#define KIT   (COX_N / (2*TPB))  // 16 iterations, 2 j's per thread per iter
#define NWAVE (TPB / 64)

__global__ __launch_bounds__(TPB) void cox_prep(const float* __restrict__ y,
                                                const float* __restrict__ theta,
                                                float2* __restrict__ se) {
    const int j = blockIdx.x * TPB + threadIdx.x;
    se[j] = make_float2(y[2 * j], __expf(theta[j]));
}

__global__ __launch_bounds__(TPB, 4) void cox_main(const float* __restrict__ y,
                                                   const float* __restrict__ theta,
                                                   const float2* __restrict__ se,
                                                   float* __restrict__ partial) {
    const int t  = threadIdx.x;
    const int b  = blockIdx.x;
    const int i0 = b * IPB;

    float st[IPB], acc[IPB];
#pragma unroll
    for (int r = 0; r < IPB; ++r) { st[r] = se[i0 + r].x; acc[r] = 0.f; }

    // Thread t handles j = {2t, 2t+1} + k*512: one 16B load feeds 48 VALU ops.
    const float4* se4 = (const float4*)se;
#pragma unroll 4
    for (int k = 0; k < KIT; ++k) {
        const float4 v = se4[k * TPB + t];   // (st_j0, e_j0, st_j1, e_j1)
#pragma unroll
        for (int r = 0; r < IPB; ++r) {
            acc[r] += (v.x >= st[r]) ? v.y : 0.f;
            acc[r] += (v.z >= st[r]) ? v.w : 0.f;
        }
    }

    // Reduce each accumulator across the block.
    __shared__ float s_red[IPB][NWAVE];
    const int lane = t & 63, wave = t >> 6;
#pragma unroll
    for (int r = 0; r < IPB; ++r) {
        float v = acc[r];
        for (int off = 32; off > 0; off >>= 1)
            v += __shfl_down(v, off, 64);
        if (lane == 0) s_red[r][wave] = v;
    }
    __syncthreads();

    if (wave == 0) {
        float term = 0.f;
        if (t < IPB) {
            float risk = 0.f;
#pragma unroll
            for (int w = 0; w < NWAVE; ++w) risk += s_red[t][w];
            const int   i      = i0 + t;
            const float censor = (y[2 * i + 1] != 0.f) ? 1.f : 0.f;
            term = (theta[i] - __logf(risk)) * censor;
        }
        term += __shfl_down(term, 4, 64);
        term += __shfl_down(term, 2, 64);
        term += __shfl_down(term, 1, 64);
        if (t == 0) partial[b] = term;
    }
}

__global__ __launch_bounds__(TPB) void cox_fin(const float* __restrict__ partial,
                                               float* __restrict__ out) {
    const int t = threadIdx.x;
    float v = partial[t] + partial[t + 256] + partial[t + 512] + partial[t + 768];
    for (int off = 32; off > 0; off >>= 1)
        v += __shfl_down(v, off, 64);
    __shared__ float red[NWAVE];
    if ((t & 63) == 0) red[t >> 6] = v;
    __syncthreads();
    if (t == 0) out[0] = -(red[0] + red[1] + red[2] + red[3]) / (float)COX_N;
}

extern "C" void kernel_launch(void* const* d_in, const int* in_sizes, int n_in,
                              void* d_out, int out_size, void* d_ws, size_t ws_size,
                              hipStream_t stream) {
    const float* y     = (const float*)d_in[0];  // (N,2): [survtime, censor]
    const float* theta = (const float*)d_in[1];  // (N,1)
    float2* se   = (float2*)d_ws;                          // 64 KB packed (st, e)
    float*  part = (float*)((char*)d_ws + COX_N * 8);      // 4 KB partials
    float*  out  = (float*)d_out;

    cox_prep<<<dim3(COX_N / TPB), dim3(TPB), 0, stream>>>(y, theta, se);
    cox_main<<<dim3(NBLK), dim3(TPB), 0, stream>>>(y, theta, se, part);
    cox_fin<<<dim3(1), dim3(TPB), 0, stream>>>(part, out);
}